// Round 2
// baseline (379.545 us; speedup 1.0000x reference)
//
#include <hip/hip_runtime.h>

#define NTOK 49
#define CH   128
#define NHEAD 4
#define SCALE 0.17677669529663687f   // 32^-0.5

typedef __bf16 bf16x8 __attribute__((ext_vector_type(8)));
typedef short  s16x8  __attribute__((ext_vector_type(8)));
typedef float  f32x4  __attribute__((ext_vector_type(4)));

__device__ __forceinline__ unsigned short f2bf(float f) {
  unsigned int u = __builtin_bit_cast(unsigned int, f);
  u += 0x7FFFu + ((u >> 16) & 1u);          // RNE
  return (unsigned short)(u >> 16);
}

__device__ __forceinline__ f32x4 mfma_bf16(s16x8 a, s16x8 b, f32x4 c) {
  return __builtin_amdgcn_mfma_f32_16x16x32_bf16(
      __builtin_bit_cast(bf16x8, a), __builtin_bit_cast(bf16x8, b), c, 0, 0, 0);
}

// ---------------- prep: weights -> bf16 transposed (coalesced reads), rpb expand ----------------
// ws layout: wT bf16[384][128] @0 ; pT bf16[128][128] @98304B ; rpb f32[4][49*49] @131072B
__global__ void prep_kernel(const float* __restrict__ qkv_w,
                            const float* __restrict__ proj_w,
                            const float* __restrict__ bias_table,
                            unsigned short* __restrict__ wT,
                            unsigned short* __restrict__ pT,
                            float* __restrict__ rpb) {
  int t = blockIdx.x * 256 + threadIdx.x;
  if (t < 384 * 128) {
    // qkv_w is [k=128][n=384]; t scans it linearly -> coalesced read
    int k = t / 384, n = t % 384;
    float v = qkv_w[t];
    if (n < 128) v *= SCALE;                 // fold q scale into Wq
    wT[n * 128 + k] = f2bf(v);
  } else if (t < 384 * 128 + 128 * 128) {
    int u = t - 384 * 128;
    int k = u >> 7, n = u & 127;
    pT[n * 128 + k] = f2bf(proj_w[u]);
  } else if (t < 384 * 128 + 128 * 128 + NHEAD * NTOK * NTOK) {
    int u = t - (384 * 128 + 128 * 128);
    int h = u / (NTOK * NTOK);
    int ij = u % (NTOK * NTOK);
    int i = ij / NTOK, j = ij % NTOK;
    int idx = (i / 7 - j / 7 + 6) * 13 + (i % 7 - j % 7 + 6);
    rpb[h * (NTOK * NTOK) + ij] = bias_table[idx * NHEAD + h];
  }
}

// ---------------- fused attention: 1 window / 8-wave block; wave (mh,h) = token-half x head ----
// LDS (76800 B): Xs bf16[64][136] (x tile; AO aliases)      @0      (17408 B)
//                per-head q[64][40]+k[64][40]; P[64][72] alias @17408 (40960 B)
//                per-head vT[32][72]                           @58368 (18432 B)
// Occupancy: 2 blocks/CU (153.6 KB LDS) = 16 waves/CU = 50%.
__global__ __launch_bounds__(512, 4)
void attn_fused_kernel(const float* __restrict__ x,
                       const float* __restrict__ qkv_b,
                       const float* __restrict__ proj_b,
                       const float* __restrict__ mask,
                       const unsigned short* __restrict__ wT,
                       const unsigned short* __restrict__ pT,
                       const float* __restrict__ rpb,
                       float* __restrict__ out) {
  __shared__ __align__(16) char smem_raw[76800];
  unsigned short* const Xs = (unsigned short*)smem_raw;              // [64][136]
  unsigned short* const QK = (unsigned short*)(smem_raw + 17408);
  unsigned short* const VT = (unsigned short*)(smem_raw + 58368);

  const int w    = blockIdx.x;
  const int tid  = threadIdx.x;
  const int wv   = tid >> 6;
  const int h    = wv & 3;          // head
  const int mh   = wv >> 2;         // token half: rows [mh*32, mh*32+32)
  const int lane = tid & 63;
  const int quad = lane >> 4;
  const int l16  = lane & 15;
  const int rowbase = mh * 32;

  unsigned short* const qs = QK + h * 5120;   // q [64][40]
  unsigned short* const ks = qs + 2560;       // k [64][40]
  unsigned short* const ps = QK + h * 5120;   // P [64][72] (aliases q+k after barrier 3)
  unsigned short* const vt = VT + h * 2304;   // vT [32][72]  (d-major, token minor)

  const f32x4 fzero = {0.f, 0.f, 0.f, 0.f};

  // ---- stage x[w] fp32 -> bf16 LDS (zero-pad rows 49..63) ----
  {
    const float* xw = x + (size_t)w * (NTOK * CH);
    for (int t = tid; t < NTOK * 32; t += 512) {
      const int row = t >> 5;
      const int c4  = (t & 31) << 2;
      const float4 v = *(const float4*)(xw + row * CH + c4);
      ushort4 pk;
      pk.x = f2bf(v.x); pk.y = f2bf(v.y); pk.z = f2bf(v.z); pk.w = f2bf(v.w);
      *(ushort4*)(Xs + row * 136 + c4) = pk;
    }
    for (int t = tid; t < 15 * 32; t += 512) {
      const int row = 49 + (t >> 5);
      const int c4  = (t & 31) << 2;
      ushort4 z; z.x = 0; z.y = 0; z.z = 0; z.w = 0;
      *(ushort4*)(Xs + row * 136 + c4) = z;
    }
  }
  __syncthreads();   // (1) Xs ready

  // ---- QKV GEMM: this wave computes q,k,v for rows [rowbase,rowbase+32), head h ----
  f32x4 acc[3][2][2];
#pragma unroll
  for (int p = 0; p < 3; ++p)
#pragma unroll
    for (int mt = 0; mt < 2; ++mt)
#pragma unroll
      for (int nt = 0; nt < 2; ++nt) acc[p][mt][nt] = fzero;

#pragma unroll
  for (int kt = 0; kt < 4; ++kt) {
    s16x8 a[2];
#pragma unroll
    for (int mt = 0; mt < 2; ++mt)
      a[mt] = *(const s16x8*)(Xs + (rowbase + mt * 16 + l16) * 136 + kt * 32 + quad * 8);
#pragma unroll
    for (int p = 0; p < 3; ++p) {
      s16x8 b[2];
#pragma unroll
      for (int nt = 0; nt < 2; ++nt)
        b[nt] = *(const s16x8*)(wT + (size_t)(p * 128 + h * 32 + nt * 16 + l16) * 128 +
                                kt * 32 + quad * 8);
#pragma unroll
      for (int mt = 0; mt < 2; ++mt)
#pragma unroll
        for (int nt = 0; nt < 2; ++nt)
          acc[p][mt][nt] = mfma_bf16(a[mt], b[nt], acc[p][mt][nt]);
    }
  }
  // write q, k (row-major, stride 40) and v transposed (d-major, stride 72)
#pragma unroll
  for (int p = 0; p < 3; ++p)
#pragma unroll
    for (int nt = 0; nt < 2; ++nt) {
      const int col = nt * 16 + l16;               // d within head, 0..31
      float bias = qkv_b[p * 128 + h * 32 + col];
      if (p == 0) bias *= SCALE;                   // Wq pre-scaled; match bias
#pragma unroll
      for (int mt = 0; mt < 2; ++mt)
#pragma unroll
        for (int r = 0; r < 4; ++r) {
          const int row = rowbase + mt * 16 + quad * 4 + r;   // token
          const unsigned short bv = f2bf(acc[p][mt][nt][r] + bias);
          if (p == 0)      qs[row * 40 + col] = bv;
          else if (p == 1) ks[row * 40 + col] = bv;
          else             vt[col * 72 + row] = bv;
        }
    }
  __syncthreads();   // (2) q/k/vT ready (cross-wave: k + vT shared within head pair); Xs dead

  // ---- S = q k^T : rows [rowbase,+32) x all 64 cols (K=d=32, one MFMA per tile) ----
  s16x8 qf[2], kf[4];
#pragma unroll
  for (int mt = 0; mt < 2; ++mt)
    qf[mt] = *(const s16x8*)(qs + (rowbase + mt * 16 + l16) * 40 + quad * 8);
#pragma unroll
  for (int nt = 0; nt < 4; ++nt)
    kf[nt] = *(const s16x8*)(ks + (nt * 16 + l16) * 40 + quad * 8);
  f32x4 s[2][4];
#pragma unroll
  for (int mt = 0; mt < 2; ++mt)
#pragma unroll
    for (int nt = 0; nt < 4; ++nt)
      s[mt][nt] = mfma_bf16(qf[mt], kf[nt], fzero);
  __syncthreads();   // (3) all q/k fragment reads done before P overwrites the region

  // ---- softmax numerator: logits are tiny (|S|<~2, mask in {0,-100}) -> skip max shift.
  //      exp(-1e30)=0 handles padding; row sums come from MFMA against ones (below). ----
  const float* maskw = mask + (size_t)(w & 63) * (NTOK * NTOK);
  const float* rpbh  = rpb + h * (NTOK * NTOK);
#pragma unroll
  for (int mt = 0; mt < 2; ++mt)
#pragma unroll
    for (int r = 0; r < 4; ++r) {
      const int i = rowbase + mt * 16 + quad * 4 + r;
#pragma unroll
      for (int nt = 0; nt < 4; ++nt) {
        const int j = nt * 16 + l16;
        float v = -1e30f;
        if (i < NTOK && j < NTOK) {
          const int ij = i * NTOK + j;
          v = s[mt][nt][r] + rpbh[ij] + maskw[ij];
        }
        ps[i * 72 + j] = f2bf(__expf(v));
      }
    }

  // ---- O = P v (M=32, N=32, K=64) + row-sums via MFMA with all-ones B ----
  s16x8 pf[2][2], vf[2][2], ones;
#pragma unroll
  for (int e = 0; e < 8; ++e) ones[e] = (short)0x3F80;   // bf16 1.0
#pragma unroll
  for (int mt = 0; mt < 2; ++mt)
#pragma unroll
    for (int kt = 0; kt < 2; ++kt)
      pf[mt][kt] = *(const s16x8*)(ps + (rowbase + mt * 16 + l16) * 72 + kt * 32 + quad * 8);
#pragma unroll
  for (int nt = 0; nt < 2; ++nt)
#pragma unroll
    for (int kt = 0; kt < 2; ++kt)
      vf[nt][kt] = *(const s16x8*)(vt + (nt * 16 + l16) * 72 + kt * 32 + quad * 8);

  f32x4 o[2][2], rs[2];
#pragma unroll
  for (int mt = 0; mt < 2; ++mt) {
    rs[mt] = fzero;
#pragma unroll
    for (int nt = 0; nt < 2; ++nt) o[mt][nt] = fzero;
  }
#pragma unroll
  for (int kt = 0; kt < 2; ++kt)
#pragma unroll
    for (int mt = 0; mt < 2; ++mt) {
      rs[mt] = mfma_bf16(pf[mt][kt], ones, rs[mt]);      // rowsum, C rows match o rows
#pragma unroll
      for (int nt = 0; nt < 2; ++nt)
        o[mt][nt] = mfma_bf16(pf[mt][kt], vf[nt][kt], o[mt][nt]);
    }

  // ---- AO (normalized, bf16) -> LDS [64][136] (aliases Xs; Xs dead since barrier 2) ----
  unsigned short* const ao = Xs;
#pragma unroll
  for (int mt = 0; mt < 2; ++mt)
#pragma unroll
    for (int r = 0; r < 4; ++r) {
      const float rsv  = rs[mt][r];
      const float rinv = rsv > 0.f ? 1.f / rsv : 0.f;    // pad rows sum to 0
      const int row = rowbase + mt * 16 + quad * 4 + r;
#pragma unroll
      for (int nt = 0; nt < 2; ++nt)
        ao[row * 136 + h * 32 + nt * 16 + l16] = f2bf(o[mt][nt][r] * rinv);
    }
  __syncthreads();   // (4) AO ready

  // ---- proj: out rows [rowbase,+32), cols [h*32,h*32+32) ----
  f32x4 po[2][2];
#pragma unroll
  for (int mt = 0; mt < 2; ++mt)
#pragma unroll
    for (int nt = 0; nt < 2; ++nt) po[mt][nt] = fzero;
#pragma unroll
  for (int kt = 0; kt < 4; ++kt) {
    s16x8 a[2], b[2];
#pragma unroll
    for (int mt = 0; mt < 2; ++mt)
      a[mt] = *(const s16x8*)(ao + (rowbase + mt * 16 + l16) * 136 + kt * 32 + quad * 8);
#pragma unroll
    for (int nt = 0; nt < 2; ++nt)
      b[nt] = *(const s16x8*)(pT + (size_t)(h * 32 + nt * 16 + l16) * 128 + kt * 32 + quad * 8);
#pragma unroll
    for (int mt = 0; mt < 2; ++mt)
#pragma unroll
      for (int nt = 0; nt < 2; ++nt)
        po[mt][nt] = mfma_bf16(a[mt], b[nt], po[mt][nt]);
  }
  float* outw = out + (size_t)w * (NTOK * CH);
#pragma unroll
  for (int nt = 0; nt < 2; ++nt) {
    const int col = h * 32 + nt * 16 + l16;
    const float pb = proj_b[col];
#pragma unroll
    for (int mt = 0; mt < 2; ++mt)
#pragma unroll
      for (int r = 0; r < 4; ++r) {
        const int row = rowbase + mt * 16 + quad * 4 + r;
        if (row < NTOK) outw[row * CH + col] = po[mt][nt][r] + pb;
      }
  }
}

extern "C" void kernel_launch(void* const* d_in, const int* in_sizes, int n_in,
                              void* d_out, int out_size, void* d_ws, size_t ws_size,
                              hipStream_t stream) {
  (void)in_sizes; (void)n_in; (void)out_size; (void)ws_size;
  const float* x          = (const float*)d_in[0];
  const float* qkv_w      = (const float*)d_in[1];
  const float* qkv_b      = (const float*)d_in[2];
  const float* proj_w     = (const float*)d_in[3];
  const float* proj_b     = (const float*)d_in[4];
  const float* bias_table = (const float*)d_in[5];
  const float* mask       = (const float*)d_in[6];
  float* out = (float*)d_out;

  unsigned short* wT = (unsigned short*)d_ws;          // 384*128 bf16
  unsigned short* pT = wT + 384 * 128;                 // 128*128 bf16
  float* rpb = (float*)(pT + 128 * 128);               // 4*49*49 f32 (@131072 B)

  const int prep_items = 384 * 128 + 128 * 128 + NHEAD * NTOK * NTOK;
  prep_kernel<<<(prep_items + 255) / 256, 256, 0, stream>>>(qkv_w, proj_w, bias_table,
                                                            wT, pT, rpb);
  attn_fused_kernel<<<4096, 512, 0, stream>>>(x, qkv_b, proj_b, mask, wT, pT, rpb, out);
}